// Round 8
// baseline (148.071 us; speedup 1.0000x reference)
//
#include <hip/hip_runtime.h>

// FOFE encoding: out[row, :] = sum_k alpha^(L-1-k) * onehot(char_ids[row, k])
// rows = B*W = 131072, L = 20, VOCAB = 256. Output fp32 = 128 MiB -> write-BW bound.
//
// History:
//  R1 (149.8us): 3x __syncthreads/row -> vmcnt(0) drain per row. Kernel ~47us.
//  R5 (141.0us): wave-private LDS slices, explicit compiler fences, up-front
//    id loads, no vmem loads in the store loop. Kernel ~38us by back-solve
//    (window also holds ~100us of harness fills + inter-dispatch L2 flushes).
//  R6 FAILED (absmax 1.008): fence-free ordering via alias analysis
//    miscompiled around the relaxed LDS atomicrmw. Fences are the contract.
//  R7 FAILED to compile: __builtin_nontemporal_store rejects HIP's float4
//    (a struct, not a clang vector).
//  R8: same as R7 but with a native ext_vector_type(4) float vector for the
//    LDS slice views and output pointer -- identical codegen
//    (ds_{read,write}_b128 / global_store_dwordx4), builtin-compatible.
//    Variable under test: nontemporal output stores (bypass L2 allocate on a
//    write-once 128 MiB stream; leave no dirty L2 for the inter-dispatch
//    writeback-invalidate inside the timed window).

typedef float fx4 __attribute__((ext_vector_type(4)));

constexpr int L     = 20;
constexpr int VOCAB = 256;
constexpr int BLOCK = 256;            // 4 waves per block
constexpr int GRID  = 2048;           // 8 blocks/CU -> 32 waves/CU resident
constexpr int R     = 2;              // rows per pair
constexpr int PPW   = 8;              // pairs per wave: 8192 waves * 8 * 2 = 131072 rows

__global__ __launch_bounds__(BLOCK) void fofe_kernel(
    const int* __restrict__ char_ids,
    const float* __restrict__ alpha_ptr,
    float* __restrict__ out,
    int n_rows)
{
    // 4 waves x 2 slices x 1 KiB = 8 KiB per block
    __shared__ float sm[(BLOCK / 64) * R * VOCAB];

    const int lane        = threadIdx.x & 63;
    const int wave        = threadIdx.x >> 6;
    const int wave_id     = blockIdx.x * (BLOCK >> 6) + wave;
    const int total_waves = gridDim.x * (BLOCK >> 6);

    const float alpha = *alpha_ptr;

    // Lane l (l < R*L = 40) scatters char (l % L) of row (pair*R + l/L).
    const int sub = (lane >= L) ? 1 : 0;
    const int ch  = lane - sub * L;

    // pw = alpha^(L-1-ch). Same repeated-multiply sequence as the reference;
    // R1-R5 passed with absmax ~3e-39.
    float pw = 1.0f;
    {
        float cur = 1.0f;
        #pragma unroll
        for (int e = 0; e < L; ++e) {
            if (ch == (L - 1) - e) pw = cur;   // never true for lanes >= 40
            cur *= alpha;
        }
    }

    float* smw  = sm + wave * (R * VOCAB);
    fx4*   sm4  = (fx4*)smw;                   // 2*64 fx4 per wave
    fx4*   out4 = (fx4*)out;

    const int n_pairs = n_rows / R;            // 65536
    const bool scat   = lane < R * L;

    // Blocked assignment: wave owns pairs [wave_id*PPW, wave_id*PPW+PPW).
    for (int base = wave_id * PPW; base < n_pairs; base += total_waves * PPW) {

        // ---- Up-front id loads: the ONLY vmem reads. Waits on these target
        // loads that predate any store, so no wait ever drains the write
        // stream (vmcnt is a single load+store queue on CDNA).
        int id[PPW];
        #pragma unroll
        for (int i = 0; i < PPW; ++i) {
            const int pair = base + i;
            id[i] = (scat && pair < n_pairs)
                        ? char_ids[(size_t)pair * (R * L) + lane] : 0;
        }

        // ---- Store loop: LDS ops + nt stores only; no vmem loads, no waits
        // on the write stream. Fully unrolled.
        #pragma unroll
        for (int i = 0; i < PPW; ++i) {
            const int pair = base + i;
            if (pair < n_pairs) {              // wave-uniform condition
                // zero this wave's two slices (2x ds_write_b128 per lane)
                sm4[lane]      = (fx4)(0.0f);
                sm4[lane + 64] = (fx4)(0.0f);
                asm volatile("" ::: "memory"); // zeros before atomics

                if (scat)
                    atomicAdd(&smw[sub * VOCAB + id[i]], pw);
                asm volatile("" ::: "memory"); // atomics before readback

                const fx4 v0 = sm4[lane];
                const fx4 v1 = sm4[lane + 64];
                const size_t o = (size_t)pair * (R * VOCAB / 4);
                __builtin_nontemporal_store(v0, &out4[o + lane]);
                __builtin_nontemporal_store(v1, &out4[o + 64 + lane]);
                asm volatile("" ::: "memory"); // readback before next zero
            }
        }
    }
}

extern "C" void kernel_launch(void* const* d_in, const int* in_sizes, int n_in,
                              void* d_out, int out_size, void* d_ws, size_t ws_size,
                              hipStream_t stream) {
    const int*   char_ids = (const int*)d_in[0];
    const float* alpha    = (const float*)d_in[1];
    float*       out      = (float*)d_out;
    const int    n_rows   = in_sizes[0] / L;   // 131072

    fofe_kernel<<<GRID, BLOCK, 0, stream>>>(char_ids, alpha, out, n_rows);
}

// Round 9
// 142.077 us; speedup vs baseline: 1.0422x; 1.0422x over previous
//
#include <hip/hip_runtime.h>

// FOFE encoding: out[row, :] = sum_k alpha^(L-1-k) * onehot(char_ids[row, k])
// rows = B*W = 131072, L = 20, VOCAB = 256. Output fp32 = 128 MiB -> write-BW bound.
//
// History:
//  R1 (149.8us): 3x __syncthreads/row -> vmcnt(0) drain per row. Kernel ~40us.
//  R5 (141.0us): BEST. Wave-private LDS slices, explicit compiler fences,
//    up-front id loads, zero vmem loads in the store loop -> store stream
//    never waits. Kernel ~30us by back-solve; window holds ~110us of harness
//    fills (512 MiB ws poison ~80us + 128 MiB out poison ~20us + restore).
//  R6 FAILED (absmax 1.008): fence-free ordering via alias analysis
//    miscompiled around the relaxed LDS atomicrmw. Fences are the contract.
//  R8 (148.1us): nontemporal stores neutral-to-negative. Mechanism: harness
//    poisons d_out right before the kernel, so the output lines are dirty in
//    L2; plain stores overwrite them in-cache (poison never reaches HBM),
//    nt stores force poison writeback + bypass = extra HBM write traffic.
//  R9: revert to plain stores == R5-exact, the best-measured variant. All
//    per-pipe estimates sit at/under the 22us HBM write floor; remaining
//    window deltas are below run-to-run fill variance (+-5-7us).

constexpr int L     = 20;
constexpr int VOCAB = 256;
constexpr int BLOCK = 256;            // 4 waves per block
constexpr int GRID  = 2048;           // 8 blocks/CU -> 32 waves/CU resident
constexpr int R     = 2;              // rows per pair
constexpr int PPW   = 8;              // pairs per wave: 8192 waves * 8 * 2 = 131072 rows

__global__ __launch_bounds__(BLOCK) void fofe_kernel(
    const int* __restrict__ char_ids,
    const float* __restrict__ alpha_ptr,
    float* __restrict__ out,
    int n_rows)
{
    // 4 waves x 2 slices x 1 KiB = 8 KiB per block
    __shared__ float sm[(BLOCK / 64) * R * VOCAB];

    const int lane        = threadIdx.x & 63;
    const int wave        = threadIdx.x >> 6;
    const int wave_id     = blockIdx.x * (BLOCK >> 6) + wave;
    const int total_waves = gridDim.x * (BLOCK >> 6);

    const float alpha = *alpha_ptr;

    // Lane l (l < R*L = 40) scatters char (l % L) of row (pair*R + l/L).
    const int sub = (lane >= L) ? 1 : 0;
    const int ch  = lane - sub * L;

    // pw = alpha^(L-1-ch). Same repeated-multiply sequence as the reference;
    // passing rounds show absmax ~3e-39.
    float pw = 1.0f;
    {
        float cur = 1.0f;
        #pragma unroll
        for (int e = 0; e < L; ++e) {
            if (ch == (L - 1) - e) pw = cur;   // never true for lanes >= 40
            cur *= alpha;
        }
    }

    float*  smw  = sm + wave * (R * VOCAB);
    float4* sm4  = (float4*)smw;               // 2*64 float4 per wave
    float4* out4 = (float4*)out;

    const int n_pairs = n_rows / R;            // 65536
    const bool scat   = lane < R * L;

    // Blocked assignment: wave owns pairs [wave_id*PPW, wave_id*PPW+PPW).
    for (int base = wave_id * PPW; base < n_pairs; base += total_waves * PPW) {

        // ---- Up-front id loads: the ONLY vmem reads. Waits on these target
        // loads that predate any store, so no wait ever drains the write
        // stream (vmcnt is a single load+store queue on CDNA).
        int id[PPW];
        #pragma unroll
        for (int i = 0; i < PPW; ++i) {
            const int pair = base + i;
            id[i] = (scat && pair < n_pairs)
                        ? char_ids[(size_t)pair * (R * L) + lane] : 0;
        }

        // ---- Store loop: LDS ops + stores only; no vmem loads, no waits on
        // the write stream. Fully unrolled.
        #pragma unroll
        for (int i = 0; i < PPW; ++i) {
            const int pair = base + i;
            if (pair < n_pairs) {              // wave-uniform condition
                // zero this wave's two slices (2x ds_write_b128 per lane)
                sm4[lane]      = make_float4(0.f, 0.f, 0.f, 0.f);
                sm4[lane + 64] = make_float4(0.f, 0.f, 0.f, 0.f);
                asm volatile("" ::: "memory"); // zeros before atomics

                if (scat)
                    atomicAdd(&smw[sub * VOCAB + id[i]], pw);
                asm volatile("" ::: "memory"); // atomics before readback

                const float4 v0 = sm4[lane];
                const float4 v1 = sm4[lane + 64];
                const size_t o  = (size_t)pair * (R * VOCAB / 4);
                out4[o + lane]      = v0;      // dirty-poison lines overwritten in L2
                out4[o + 64 + lane] = v1;
                asm volatile("" ::: "memory"); // readback before next zero
            }
        }
    }
}

extern "C" void kernel_launch(void* const* d_in, const int* in_sizes, int n_in,
                              void* d_out, int out_size, void* d_ws, size_t ws_size,
                              hipStream_t stream) {
    const int*   char_ids = (const int*)d_in[0];
    const float* alpha    = (const float*)d_in[1];
    float*       out      = (float*)d_out;
    const int    n_rows   = in_sizes[0] / L;   // 131072

    fofe_kernel<<<GRID, BLOCK, 0, stream>>>(char_ids, alpha, out, n_rows);
}